// Round 3
// baseline (1987.613 us; speedup 1.0000x reference)
//
#include <hip/hip_runtime.h>

// Neural-ODE RK4 over MLP 12->300->100->50->12, B=1024, T=100.
// 256 blocks x 512 threads (8 waves = 2/SIMD), 4 batch elements per block.
// Weights LDS-resident (W2/W3 chunked conflict-free), W1 in registers,
// W4 k-split + shfl reduce. Weight LDS traffic = 1x per CU per eval.

constexpr int BATCH = 1024;
constexpr int T  = 100;
constexpr int D  = 12;
constexpr int H1 = 300;
constexpr int H2 = 100;
constexpr int H3 = 50;
constexpr float NEG = 0.01f;

__device__ __forceinline__ float lrelu(float x) { return fmaxf(x, NEG * x); }
__device__ __forceinline__ float dot4(float4 a, float4 b) {
    return a.x * b.x + a.y * b.y + a.z * b.z + a.w * b.w;
}

__global__ __launch_bounds__(512, 2)
void node_rk4_kernel(const float* __restrict__ y0, const float* __restrict__ t,
                     const float* __restrict__ W1, const float* __restrict__ b1,
                     const float* __restrict__ W2, const float* __restrict__ b2,
                     const float* __restrict__ W3, const float* __restrict__ b3,
                     const float* __restrict__ W4, const float* __restrict__ b4,
                     float* __restrict__ out)
{
    // LDS: 121600+20000+2400+4864+6400+1600+800+400+208+576 = 158,848 B
    __shared__ __align__(16) float sW2c[76 * 400];  // [c][j][4k], chunk 75 zeroed
    __shared__ __align__(16) float sW3c[25 * 200];  // [c][j][4k]
    __shared__ __align__(16) float sW4 [600];       // [k][j]
    __shared__ __align__(16) float h1  [4 * 304];   // [e][304], cols 300..303 zero
    __shared__ __align__(16) float pL2 [4 * 400];   // [kq][e*100+j]; pL3 aliases all
    __shared__ __align__(16) float h2  [400];       // [e][100]
    __shared__ __align__(16) float h3  [200];       // [e][50]
    __shared__ __align__(16) float sB2 [100];
    __shared__ __align__(16) float sB3 [52];
    __shared__ __align__(16) float sx  [48];
    __shared__ __align__(16) float sxe [48];
    __shared__ __align__(16) float sks [48];

    const int tid = threadIdx.x;
    const int l   = tid & 63;
    const int w   = tid >> 6;          // wave 0..7
    const int ch  = w >> 2;            // L2 column half (0,1)
    const int kq  = w & 3;             // L2 k-quarter

    // ---- one-time staging ----
    for (int i = tid; i < H1 * H2; i += 512) {       // W2 [k=300][j=100]
        int k = i / 100, j = i - k * 100;
        sW2c[(k >> 2) * 400 + j * 4 + (k & 3)] = W2[i];
    }
    for (int i = tid; i < 400; i += 512) sW2c[75 * 400 + i] = 0.0f;  // pad chunk
    for (int i = tid; i < H2 * H3; i += 512) {       // W3 [k=100][j=50]
        int k = i / 50, j = i - k * 50;
        sW3c[(k >> 2) * 200 + j * 4 + (k & 3)] = W3[i];
    }
    for (int i = tid; i < H3 * D; i += 512) sW4[i] = W4[i];
    for (int i = tid; i < 4 * 304; i += 512) h1[i] = 0.0f;           // zero pads
    if (tid < H2) sB2[tid] = b2[tid];
    if (tid < H3) sB3[tid] = b3[tid];

    // ---- register-resident W1 column (col = tid) + b1 ----
    float w1r[12];
    float rb1 = 0.0f;
#pragma unroll
    for (int k = 0; k < 12; ++k) w1r[k] = 0.0f;
    if (tid < H1) {
        rb1 = b1[tid];
#pragma unroll
        for (int k = 0; k < 12; ++k) w1r[k] = W1[k * H1 + tid];
    }

    // ---- L4 lane constants: tid<192 -> (e4, j4, kq4) ----
    const int e4  = tid / 48;
    const int r4  = tid - e4 * 48;
    const int j4  = r4 >> 2;
    const int kq4 = r4 & 3;
    const float rb4 = (tid < 192) ? b4[j4] : 0.0f;

    // ---- init x0, write out[:,0,:] ----
    if (tid < 48) {
        int e = tid / 12, j = tid - e * 12;
        int g = (blockIdx.x * 4 + e) * (T * D) + j;
        float v = y0[g];
        sx[tid] = v;
        out[g]  = v;
    }
    __syncthreads();

    for (int s = 0; s < T - 1; ++s) {
        const float dt = t[s + 1] - t[s];            // uniform (t row 0)
        for (int ev = 0; ev < 4; ++ev) {
            const float* xin = ev ? sxe : sx;

            // ===== L1: 12 -> 300, col = tid, W1 in regs =====
            if (tid < H1) {
#pragma unroll
                for (int e = 0; e < 4; ++e) {
                    const float4 x0 = *(const float4*)(xin + e * 12);
                    const float4 x1 = *(const float4*)(xin + e * 12 + 4);
                    const float4 x2 = *(const float4*)(xin + e * 12 + 8);
                    float acc = rb1;
                    acc += x0.x * w1r[0] + x0.y * w1r[1] + x0.z * w1r[2] + x0.w * w1r[3];
                    acc += x1.x * w1r[4] + x1.y * w1r[5] + x1.z * w1r[6] + x1.w * w1r[7];
                    acc += x2.x * w1r[8] + x2.y * w1r[9] + x2.z * w1r[10] + x2.w * w1r[11];
                    h1[e * 304 + tid] = lrelu(acc);
                }
            }
            __syncthreads();                         // A: h1 ready

            // ===== L2: 300 -> 100, wave (ch,kq), lanes l<50 own col ch*50+l =====
            if (l < 50) {
                float a2[4] = {0.f, 0.f, 0.f, 0.f};
                const float* wbase = sW2c + (ch * 50 + l) * 4;
#pragma unroll 4
                for (int i = 0; i < 19; ++i) {       // c = kq+4i <= 75 (chunk 75 = 0s)
                    const int c = kq + 4 * i;
                    const float4 wv = *(const float4*)(wbase + c * 400);
#pragma unroll
                    for (int e = 0; e < 4; ++e) {
                        const float4 h = *(const float4*)(h1 + e * 304 + c * 4);
                        a2[e] += dot4(h, wv);
                    }
                }
#pragma unroll
                for (int e = 0; e < 4; ++e)
                    pL2[kq * 400 + e * 100 + ch * 50 + l] = a2[e];
            }
            __syncthreads();                         // B: pL2 ready

            // ===== h2 reduce: 4 partials =====
            if (tid < 400) {
                const int j = tid % 100;
                float v = sB2[j] + pL2[tid] + pL2[400 + tid] + pL2[800 + tid] + pL2[1200 + tid];
                h2[tid] = lrelu(v);
            }
            __syncthreads();                         // C: h2 ready

            // ===== L3: 100 -> 50, k-split over 8 waves, lanes l<50 =====
            if (l < 50) {
                float a3[4] = {0.f, 0.f, 0.f, 0.f};
                const float* wbase = sW3c + l * 4;
                for (int c = w; c < 25; c += 8) {
                    const float4 wv = *(const float4*)(wbase + c * 200);
#pragma unroll
                    for (int e = 0; e < 4; ++e) {
                        const float4 h = *(const float4*)(h2 + e * 100 + c * 4);
                        a3[e] += dot4(h, wv);
                    }
                }
#pragma unroll
                for (int e = 0; e < 4; ++e)          // pL3 aliases pL2 (bar C passed)
                    pL2[w * 200 + e * 50 + l] = a3[e];
            }
            __syncthreads();                         // D: pL3 ready

            // ===== h3 reduce: 8 partials =====
            if (tid < 200) {
                const int k = tid % 50;
                float v = sB3[k];
#pragma unroll
                for (int h = 0; h < 8; ++h) v += pL2[h * 200 + tid];
                h3[tid] = lrelu(v);
            }
            __syncthreads();                         // E: h3 ready

            // ===== L4: 50 -> 12, k-split x4 + shfl reduce, fused RK4 =====
            if (tid < 192) {
                float acc = 0.0f;
                for (int k = kq4; k < H3; k += 4)
                    acc += h3[e4 * 50 + k] * sW4[k * 12 + j4];
                acc += __shfl_xor(acc, 1);
                acc += __shfl_xor(acc, 2);
                if (kq4 == 0) {
                    acc += rb4;
                    const int bi = e4 * 12 + j4;
                    const float xc = sx[bi];
                    if (ev == 0) {
                        sks[bi] = acc;
                        sxe[bi] = xc + 0.5f * dt * acc;
                    } else if (ev == 1) {
                        sks[bi] += 2.0f * acc;
                        sxe[bi] = xc + 0.5f * dt * acc;
                    } else if (ev == 2) {
                        sks[bi] += 2.0f * acc;
                        sxe[bi] = xc + dt * acc;
                    } else {
                        const float xn = xc + dt * (1.0f / 6.0f) * (sks[bi] + acc);
                        sx[bi] = xn;
                        out[(blockIdx.x * 4 + e4) * (T * D) + (s + 1) * D + j4] = xn;
                    }
                }
            }
            __syncthreads();                         // F: state ready
        }
    }
}

extern "C" void kernel_launch(void* const* d_in, const int* in_sizes, int n_in,
                              void* d_out, int out_size, void* d_ws, size_t ws_size,
                              hipStream_t stream) {
    const float* y0 = (const float*)d_in[0];
    const float* t  = (const float*)d_in[1];
    const float* W1 = (const float*)d_in[2];
    const float* b1 = (const float*)d_in[3];
    const float* W2 = (const float*)d_in[4];
    const float* b2 = (const float*)d_in[5];
    const float* W3 = (const float*)d_in[6];
    const float* b3 = (const float*)d_in[7];
    const float* W4 = (const float*)d_in[8];
    const float* b4 = (const float*)d_in[9];
    float* out = (float*)d_out;

    node_rk4_kernel<<<BATCH / 4, 512, 0, stream>>>(y0, t, W1, b1, W2, b2, W3, b3, W4, b4, out);
}

// Round 4
// 1137.619 us; speedup vs baseline: 1.7472x; 1.7472x over previous
//
#include <hip/hip_runtime.h>

// Neural-ODE RK4 over MLP 12->300->100->50->12, B=1024, T=100.
// 256 blocks x 512 threads (8 waves), 4 batch elements per block.
// Inverted dataflow: W1/W2/W4 in REGISTERS (distributed across threads),
// activations broadcast from LDS (uniform-address reads, conflict-free,
// compile-time offsets). W3 streamed from LDS (20KB, chunked layout).
// 5 barriers/eval. LDS padded >80KB to force 1 block/CU.

constexpr int TT = 100;
constexpr int D  = 12;
constexpr int H1 = 300;
constexpr int H2 = 100;
constexpr int H3 = 50;
constexpr float NEG = 0.01f;

__device__ __forceinline__ float lrelu(float x) { return fmaxf(x, NEG * x); }

__global__ __launch_bounds__(512)
void node_rk4_kernel(const float* __restrict__ y0, const float* __restrict__ t,
                     const float* __restrict__ W1, const float* __restrict__ b1,
                     const float* __restrict__ W2, const float* __restrict__ b2,
                     const float* __restrict__ W3, const float* __restrict__ b3,
                     const float* __restrict__ W4, const float* __restrict__ b4,
                     float* __restrict__ out)
{
    __shared__ __align__(16) float sW3c[25 * 200];   // [c][j][4] chunked W3 (20 KB)
    __shared__ __align__(16) float h1[4 * 304];      // pitch 304; cols 300-303 zeroed
    __shared__ __align__(16) float pL2[16 * 104];    // [(kq*4+e)][104] partials
    __shared__ __align__(16) float h2[4 * 104];      // pitch 104
    __shared__ __align__(16) float h3[4 * 52];       // pitch 52; cols 50,51 zeroed
    __shared__ __align__(16) float sx[48];
    __shared__ __align__(16) float sxe[48];
    __shared__ __align__(16) float sks[48];
    __shared__ float sb2[100];
    __shared__ float sb3[50];
    __shared__ float st[100];
    __shared__ float padlds[11700];                  // LDS pad -> 1 block/CU

    const int tid = threadIdx.x;
    const int l   = tid & 63;
    const int w   = tid >> 6;              // wave 0..7
    const int kq  = w & 3;                 // L2 k-quarter (chunks c == kq mod 4)
    const int jh  = w >> 2;                // L2 column half
    const bool l2act = (l < 50);
    const int jcol = jh * 50 + (l2act ? l : 49);

    // ---- register-resident weights ----
    float w2v[76];                          // W2[k=(kq+4i)*4+jj][jcol]
#pragma unroll
    for (int i = 0; i < 19; ++i) {
#pragma unroll
        for (int jj = 0; jj < 4; ++jj) {
            const int k = (kq + 4 * i) * 4 + jj;        // <= 303
            w2v[4 * i + jj] = (l2act && k < H1) ? W2[k * H2 + jcol] : 0.0f;
        }
    }
    float w1v[12];
    float rb1 = 0.0f;
    if (tid < H1) {
        rb1 = b1[tid];
#pragma unroll
        for (int k = 0; k < 12; ++k) w1v[k] = W1[k * H1 + tid];
    } else {
#pragma unroll
        for (int k = 0; k < 12; ++k) w1v[k] = 0.0f;
    }
    const int u4 = tid - 256;              // L4 on waves 4-6
    const bool l4act = (u4 >= 0 && u4 < 192);
    int e4 = 0, j4 = 0, kq4 = 0;
    float b4v = 0.0f;
    if (l4act) {
        e4 = u4 / 48; const int r = u4 - e4 * 48; j4 = r >> 2; kq4 = r & 3;
        b4v = b4[j4];
    }
    float w4v[13];                          // W4[k=kq4*13+i][j4]
#pragma unroll
    for (int i = 0; i < 13; ++i) {
        const int k = kq4 * 13 + i;
        w4v[i] = (l4act && k < H3) ? W4[k * D + j4] : 0.0f;
    }

    // ---- LDS staging ----
    for (int i = tid; i < H2 * H3; i += 512) {          // W3 [k=100][j=50]
        const int k = i / H3, j = i - k * H3;
        sW3c[(k >> 2) * 200 + j * 4 + (k & 3)] = W3[i];
    }
    if (tid < H2) sb2[tid] = b2[tid];
    if (tid < H3) sb3[tid] = b3[tid];
    if (tid < TT) st[tid] = t[tid];                     // t row 0
    if (tid < 16) h1[(tid >> 2) * 304 + 300 + (tid & 3)] = 0.0f;   // zero pads
    if (tid < 8)  h3[(tid >> 1) * 52 + 50 + (tid & 1)] = 0.0f;
    if (tid < 48) {                                     // init x0, out[:,0,:]
        const int e = tid / 12, j = tid - e * 12;
        const int g = (blockIdx.x * 4 + e) * (TT * D) + j;
        const float v = y0[g];
        sx[tid] = v;
        out[g]  = v;
    }
    padlds[tid] = 0.0f;
    __syncthreads();
    if (st[0] > 1.0e30f) out[0] = padlds[tid];          // never true; keeps pad live

    for (int s = 0; s < TT - 1; ++s) {
        const float dt = st[s + 1] - st[s];
#pragma unroll 1
        for (int ev = 0; ev < 4; ++ev) {
            const float* xin = ev ? sxe : sx;

            // ===== L1: 12 -> 300, col = tid, weights in regs =====
            if (tid < H1) {
#pragma unroll
                for (int e = 0; e < 4; ++e) {
                    const float4 x0 = *(const float4*)(xin + e * 12);
                    const float4 x1 = *(const float4*)(xin + e * 12 + 4);
                    const float4 x2 = *(const float4*)(xin + e * 12 + 8);
                    float a = rb1;
                    a = fmaf(x0.x, w1v[0], a);  a = fmaf(x0.y, w1v[1], a);
                    a = fmaf(x0.z, w1v[2], a);  a = fmaf(x0.w, w1v[3], a);
                    a = fmaf(x1.x, w1v[4], a);  a = fmaf(x1.y, w1v[5], a);
                    a = fmaf(x1.z, w1v[6], a);  a = fmaf(x1.w, w1v[7], a);
                    a = fmaf(x2.x, w1v[8], a);  a = fmaf(x2.y, w1v[9], a);
                    a = fmaf(x2.z, w1v[10], a); a = fmaf(x2.w, w1v[11], a);
                    h1[e * 304 + tid] = lrelu(a);
                }
            }
            __syncthreads();                            // A: h1 ready

            // ===== L2: 300 -> 100, weights in regs, broadcast act reads =====
            {
                float a0 = 0.f, a1 = 0.f, a2 = 0.f, a3 = 0.f;
                const float* hb = h1 + kq * 4;          // k = 4*kq + 16*i
#pragma unroll
                for (int i = 0; i < 19; ++i) {
                    const float4 he0 = *(const float4*)(hb + 0 * 304 + 16 * i);
                    const float4 he1 = *(const float4*)(hb + 1 * 304 + 16 * i);
                    const float4 he2 = *(const float4*)(hb + 2 * 304 + 16 * i);
                    const float4 he3 = *(const float4*)(hb + 3 * 304 + 16 * i);
                    a0 = fmaf(he0.x, w2v[4*i+0], a0); a0 = fmaf(he0.y, w2v[4*i+1], a0);
                    a0 = fmaf(he0.z, w2v[4*i+2], a0); a0 = fmaf(he0.w, w2v[4*i+3], a0);
                    a1 = fmaf(he1.x, w2v[4*i+0], a1); a1 = fmaf(he1.y, w2v[4*i+1], a1);
                    a1 = fmaf(he1.z, w2v[4*i+2], a1); a1 = fmaf(he1.w, w2v[4*i+3], a1);
                    a2 = fmaf(he2.x, w2v[4*i+0], a2); a2 = fmaf(he2.y, w2v[4*i+1], a2);
                    a2 = fmaf(he2.z, w2v[4*i+2], a2); a2 = fmaf(he2.w, w2v[4*i+3], a2);
                    a3 = fmaf(he3.x, w2v[4*i+0], a3); a3 = fmaf(he3.y, w2v[4*i+1], a3);
                    a3 = fmaf(he3.z, w2v[4*i+2], a3); a3 = fmaf(he3.w, w2v[4*i+3], a3);
                }
                if (l2act) {
                    pL2[(kq * 4 + 0) * 104 + jcol] = a0;
                    pL2[(kq * 4 + 1) * 104 + jcol] = a1;
                    pL2[(kq * 4 + 2) * 104 + jcol] = a2;
                    pL2[(kq * 4 + 3) * 104 + jcol] = a3;
                }
            }
            __syncthreads();                            // B: partials ready

            // ===== reduce -> h2 (4 partials) =====
            if (tid < 400) {
                const int e = tid / 100, j = tid - e * 100;
                float v = sb2[j];
                v += pL2[(0 + e) * 104 + j];
                v += pL2[(4 + e) * 104 + j];
                v += pL2[(8 + e) * 104 + j];
                v += pL2[(12 + e) * 104 + j];
                h2[e * 104 + j] = lrelu(v);
            }
            __syncthreads();                            // C: h2 ready

            // ===== L3: 100 -> 50, waves 0-3 (e = w), LDS weights =====
            if (w < 4 && l < H3) {
                float a = sb3[l];
                const float* hb2 = h2 + w * 104;
                const float* wb  = sW3c + l * 4;
#pragma unroll
                for (int c = 0; c < 25; ++c) {
                    const float4 wv = *(const float4*)(wb + c * 200);
                    const float4 hv = *(const float4*)(hb2 + c * 4);
                    a = fmaf(hv.x, wv.x, a); a = fmaf(hv.y, wv.y, a);
                    a = fmaf(hv.z, wv.z, a); a = fmaf(hv.w, wv.w, a);
                }
                h3[w * 52 + l] = lrelu(a);
            }
            __syncthreads();                            // E: h3 ready

            // ===== L4: 50 -> 12, waves 4-6, reg weights + shfl reduce =====
            if (l4act) {
                float a = 0.f;
                const float* hb3 = h3 + e4 * 52 + kq4 * 13;
#pragma unroll
                for (int i = 0; i < 13; ++i)
                    a = fmaf(hb3[i], w4v[i], a);        // pads: h3=0, w4v=0
                a += __shfl_xor(a, 1);
                a += __shfl_xor(a, 2);
                if (kq4 == 0) {
                    a += b4v;
                    const int bi = e4 * 12 + j4;
                    const float xc = sx[bi];
                    if (ev == 0)      { sks[bi] = a;        sxe[bi] = xc + 0.5f * dt * a; }
                    else if (ev == 1) { sks[bi] += 2.f * a; sxe[bi] = xc + 0.5f * dt * a; }
                    else if (ev == 2) { sks[bi] += 2.f * a; sxe[bi] = xc + dt * a; }
                    else {
                        const float xn = xc + dt * (1.0f / 6.0f) * (sks[bi] + a);
                        sx[bi] = xn;
                        out[(blockIdx.x * 4 + e4) * (TT * D) + (s + 1) * D + j4] = xn;
                    }
                }
            }
            __syncthreads();                            // F: state ready
        }
    }
}

extern "C" void kernel_launch(void* const* d_in, const int* in_sizes, int n_in,
                              void* d_out, int out_size, void* d_ws, size_t ws_size,
                              hipStream_t stream) {
    const float* y0 = (const float*)d_in[0];
    const float* t  = (const float*)d_in[1];
    const float* W1 = (const float*)d_in[2];
    const float* b1 = (const float*)d_in[3];
    const float* W2 = (const float*)d_in[4];
    const float* b2 = (const float*)d_in[5];
    const float* W3 = (const float*)d_in[6];
    const float* b3 = (const float*)d_in[7];
    const float* W4 = (const float*)d_in[8];
    const float* b4 = (const float*)d_in[9];
    float* out = (float*)d_out;

    node_rk4_kernel<<<256, 512, 0, stream>>>(y0, t, W1, b1, W2, b2, W3, b3, W4, b4, out);
}